// Round 6
// baseline (1006.132 us; speedup 1.0000x reference)
//
#include <hip/hip_runtime.h>
#include <math.h>

// PolaLinearAttention, MI355X round 6.
// R5 counters: k1 MfmaUtil 10%, VALU 24%, HBM 27%, occ 32% -> latency-chain
// bound; fix = register-prefetch next K-tile so global latency overlaps MFMA.
// k2 was ~170us LDS-read bound (9 ds_read_b32 per 18 FMA) -> MFMA rewrite
// (96x64 x 64x64 per tile, ones-column computes km in the same GEMM).
// Layout: intermediates channel-major T: (b*384+c)*16384 + n (bf16).
//   qsT,gT,ksT in ws; vT in d_out first half (dead before k5 writes).
//   W2T[1536][384]=[Wqg|Wkv]^T bf16, WpT[384][384]=Wproj^T bf16 in ws.
// ws: flag|stats(0.6MB)|qsT,gT,ksT(151MB)|W2T,WpT(1.5MB) ~= 154MB (guarded).

#define NB 4
#define NTOK 16384
#define CDIM 384
#define NHEAD 8
#define HDIM 48
#define IMGH 128
#define IMGW 128

typedef unsigned short u16;
typedef __attribute__((ext_vector_type(8))) short bf16x8;
typedef __attribute__((ext_vector_type(4))) float f32x4;

__device__ __forceinline__ float bf2f(u16 u) {
  return __uint_as_float(((unsigned)u) << 16);
}
__device__ __forceinline__ u16 f2bf(float f) {
  unsigned u = __float_as_uint(f);
  u += 0x7FFF + ((u >> 16) & 1);   // RNE
  return (u16)(u >> 16);
}
// |v|^p, safe: never logs non-positive, never inf/NaN.
__device__ __forceinline__ float pow_mag(float r, float p) {
  if (r < 1e-20f) return 0.0f;
  return exp2f(fminf(p * log2f(r), 80.0f));
}
__device__ __forceinline__ float ldx1(const void* p, size_t i, bool f32) {
  return f32 ? ((const float*)p)[i] : bf2f(((const u16*)p)[i]);
}

// ---------------- k0: dtype detector ------------------------------------------------
__global__ __launch_bounds__(256) void k0_detect(const void* __restrict__ x,
                                                 int* __restrict__ flag) {
  __shared__ int s[256];
  const u16* p = (const u16*)x;
  const int t = threadIdx.x;
  int good = 0;
#pragma unroll
  for (int i = 0; i < 16; ++i) {
    const u16 w = p[t * 16 + i];
    const int e = (w >> 7) & 0xFF;
    good += (e >= 0x60 && e <= 0x85) ? 1 : 0;
  }
  s[t] = good;
  __syncthreads();
  for (int o = 128; o > 0; o >>= 1) {
    if (t < o) s[t] += s[t + o];
    __syncthreads();
  }
  if (t == 0) *flag = (s[0] >= (4096 * 4) / 5) ? 0 : 1;  // 0 = bf16, 1 = fp32
}

// ---------------- kprep: bf16 transposed weights -----------------------------------
__global__ __launch_bounds__(256) void kprep(
    const void* __restrict__ Wqg, const void* __restrict__ Wkv,
    const void* __restrict__ Wp, const int* __restrict__ flag,
    u16* __restrict__ W2T, u16* __restrict__ WpT)
{
  const bool f32 = (*flag != 0);
  const int idx = blockIdx.x * 256 + threadIdx.x;
  if (idx < 1536 * 384) {
    const int n = idx / 384, k = idx - n * 384;
    const float v = (n < 768) ? ldx1(Wqg, (size_t)k * 768 + n, f32)
                              : ldx1(Wkv, (size_t)k * 768 + (n - 768), f32);
    W2T[idx] = f2bf(v);
  } else {
    const int j = idx - 1536 * 384;
    if (j < 384 * 384) {
      const int n = j / 384, k = j - n * 384;
      WpT[j] = f2bf(ldx1(Wp, (size_t)k * 384 + n, f32));
    }
  }
}

// ---------------- k1: MFMA GEMM x @ [Wqg|Wkv], reg-prefetch pipeline ---------------
__global__ __launch_bounds__(256) void k1_mfma(
    const void* __restrict__ x, const u16* __restrict__ W2T,
    const void* __restrict__ pos_enc, const void* __restrict__ scale_p,
    const int* __restrict__ flag,
    u16* __restrict__ qsT, u16* __restrict__ gT, u16* __restrict__ ksT, u16* __restrict__ vT)
{
  const bool f32 = (*flag != 0);
  __shared__ __align__(16) u16 Asm[128 * 64];   // [m][k], XOR-swizzled chunks
  __shared__ __align__(16) u16 Bsm[128 * 64];   // [n][k]
  const int t = threadIdx.x;
  const int n0 = blockIdx.x * 128;
  const int m0 = blockIdx.y * 128;
  const int wave = t >> 6, lane = t & 63;
  const int wr = wave >> 1, wc = wave & 1;
  const int lm = lane & 15, lq = lane >> 4;

  int ro[4], co[4], lo[4];
#pragma unroll
  for (int i = 0; i < 4; ++i) {
    const int chunk = t + i * 256;
    ro[i] = chunk >> 3; co[i] = chunk & 7;
    lo[i] = ro[i] * 64 + ((co[i] ^ (ro[i] & 7)) * 8);
  }

  f32x4 acc[4][4] = {};
  uint4 aU[4], bU[4];
  float4 aF[4][2];

  // prologue: load K-tile 0 into regs
#pragma unroll
  for (int i = 0; i < 4; ++i) {
    if (f32) {
      const float* xp = (const float*)x + (size_t)(m0 + ro[i]) * CDIM + co[i] * 8;
      aF[i][0] = *(const float4*)xp;
      aF[i][1] = *(const float4*)(xp + 4);
    } else {
      aU[i] = *(const uint4*)((const u16*)x + (size_t)(m0 + ro[i]) * CDIM + co[i] * 8);
    }
    bU[i] = *(const uint4*)(W2T + (size_t)(n0 + ro[i]) * CDIM + co[i] * 8);
  }

  for (int k0 = 0; k0 < CDIM; k0 += 64) {
    if (k0) __syncthreads();          // prev tile fully consumed before overwrite
#pragma unroll
    for (int i = 0; i < 4; ++i) {
      if (f32) {
        *(ushort4*)&Asm[lo[i]] = make_ushort4(f2bf(aF[i][0].x), f2bf(aF[i][0].y),
                                              f2bf(aF[i][0].z), f2bf(aF[i][0].w));
        *(ushort4*)&Asm[lo[i] + 4] = make_ushort4(f2bf(aF[i][1].x), f2bf(aF[i][1].y),
                                                  f2bf(aF[i][1].z), f2bf(aF[i][1].w));
      } else {
        *(uint4*)&Asm[lo[i]] = aU[i];
      }
      *(uint4*)&Bsm[lo[i]] = bU[i];
    }
    __syncthreads();
    if (k0 < CDIM - 64) {             // prefetch next K-tile; flies during MFMA
      const int kn = k0 + 64;
#pragma unroll
      for (int i = 0; i < 4; ++i) {
        if (f32) {
          const float* xp = (const float*)x + (size_t)(m0 + ro[i]) * CDIM + kn + co[i] * 8;
          aF[i][0] = *(const float4*)xp;
          aF[i][1] = *(const float4*)(xp + 4);
        } else {
          aU[i] = *(const uint4*)((const u16*)x + (size_t)(m0 + ro[i]) * CDIM + kn + co[i] * 8);
        }
        bU[i] = *(const uint4*)(W2T + (size_t)(n0 + ro[i]) * CDIM + kn + co[i] * 8);
      }
    }
#pragma unroll
    for (int kh = 0; kh < 2; ++kh) {
      bf16x8 af[4], bfr[4];
#pragma unroll
      for (int r = 0; r < 4; ++r) {
        const int row = wr * 64 + r * 16 + lm;
        af[r] = *(const bf16x8*)&Asm[row * 64 + (((kh * 4 + lq) ^ (row & 7)) * 8)];
      }
#pragma unroll
      for (int cb = 0; cb < 4; ++cb) {
        const int row = wc * 64 + cb * 16 + lm;
        bfr[cb] = *(const bf16x8*)&Bsm[row * 64 + (((kh * 4 + lq) ^ (row & 7)) * 8)];
      }
#pragma unroll
      for (int r = 0; r < 4; ++r)
#pragma unroll
        for (int cb = 0; cb < 4; ++cb)
          acc[r][cb] = __builtin_amdgcn_mfma_f32_16x16x32_bf16(af[r], bfr[cb], acc[r][cb], 0, 0, 0);
    }
  }
  // epilogue: C/D layout col=lane&15 (=n), row=(lane>>4)*4+reg (=token)
  const int b = m0 >> 14;
  const int region = n0 / CDIM;
#pragma unroll
  for (int cb = 0; cb < 4; ++cb) {
    const int cg = n0 + wc * 64 + cb * 16 + lm;
    const int c = cg - region * CDIM;
    float inv = 1.0f;
    if (region == 0 || region == 2) inv = 1.0f / log1pf(expf(ldx1(scale_p, c, f32)));
#pragma unroll
    for (int r = 0; r < 4; ++r) {
      const int tok = (m0 & (NTOK - 1)) + wr * 64 + r * 16 + lq * 4;
      const size_t base = ((size_t)(b * CDIM + c)) * NTOK + tok;
      const f32x4 v = acc[r][cb];
      if (region == 0) {
        *(ushort4*)(qsT + base) =
            make_ushort4(f2bf(v[0] * inv), f2bf(v[1] * inv), f2bf(v[2] * inv), f2bf(v[3] * inv));
      } else if (region == 1) {
        *(ushort4*)(gT + base) = make_ushort4(f2bf(v[0]), f2bf(v[1]), f2bf(v[2]), f2bf(v[3]));
      } else if (region == 2) {
        const float p0 = ldx1(pos_enc, (size_t)(tok + 0) * CDIM + c, f32);
        const float p1 = ldx1(pos_enc, (size_t)(tok + 1) * CDIM + c, f32);
        const float p2 = ldx1(pos_enc, (size_t)(tok + 2) * CDIM + c, f32);
        const float p3 = ldx1(pos_enc, (size_t)(tok + 3) * CDIM + c, f32);
        *(ushort4*)(ksT + base) = make_ushort4(f2bf((v[0] + p0) * inv), f2bf((v[1] + p1) * inv),
                                               f2bf((v[2] + p2) * inv), f2bf((v[3] + p3) * inv));
      } else {
        *(ushort4*)(vT + base) = make_ushort4(f2bf(v[0]), f2bf(v[1]), f2bf(v[2]), f2bf(v[3]));
      }
    }
  }
}

// ---------------- k2: MFMA stats: [kk(96) x tok] @ [tok x (v|1|0)(64)] -------------
// Output 96x64: cols 0..47 -> kvm, col 48 (ones) -> km. 16-way K-split, atomics.
__global__ __launch_bounds__(256) void k2_stats(
    const u16* __restrict__ ksT, const u16* __restrict__ vT,
    const void* __restrict__ power_p, const int* __restrict__ flag,
    float* __restrict__ km, float* __restrict__ kvm)
{
  const bool f32 = (*flag != 0);
  __shared__ __align__(16) u16 kkA[96][72];   // bf16 features [M][K-tile], 144B rows
  __shared__ __align__(16) u16 vB[64][72];    // bf16 [N][K-tile]; rows 48..63 static
  __shared__ float pw[48];
  const int bh = blockIdx.x;
  const int b = bh >> 3, h = bh & 7;
  const int t = threadIdx.x;
  if (t < 48) pw[t] = 1.0f + 4.0f / (1.0f + expf(-ldx1(power_p, h * HDIM + t, f32)));
  for (int i = t; i < 16 * 72; i += 256) {    // rows 48..63: [1,0,0,...]
    const int r = 48 + i / 72, c = i % 72;
    vB[r][c] = (r == 48) ? (u16)0x3F80 : (u16)0;
  }
  __syncthreads();

  const int wave = t >> 6, lane = t & 63;
  const int wr = wave >> 1, wc = wave & 1;    // wr: M half (48), wc: N half (32)
  const int lm = lane & 15, lq = lane >> 4;

  f32x4 acc[3][2] = {};
  const u16* ksbase = ksT + ((size_t)(b * CDIM + h * HDIM)) * NTOK;
  const u16* vbase  = vT  + ((size_t)(b * CDIM + h * HDIM)) * NTOK;
  const int n0base = blockIdx.y * 1024;

  for (int tile = 0; tile < 16; ++tile) {
    const int n0 = n0base + tile * 64;
    for (int i = t; i < 768; i += 256) {      // 48 ch x 16 quad4
      const int c = i >> 4, qd = (i & 15) * 4;
      const ushort4 kq = *(const ushort4*)(ksbase + (size_t)c * NTOK + n0 + qd);
      const ushort4 vq = *(const ushort4*)(vbase  + (size_t)c * NTOK + n0 + qd);
      const float p = pw[c];
      const float kf[4] = {bf2f(kq.x), bf2f(kq.y), bf2f(kq.z), bf2f(kq.w)};
      u16 kp[4], kn[4];
#pragma unroll
      for (int jj = 0; jj < 4; ++jj) {
        const u16 fb = f2bf(pow_mag(fabsf(kf[jj]), p));
        kp[jj] = (kf[jj] > 0.f) ? fb : (u16)0;
        kn[jj] = (kf[jj] < 0.f) ? fb : (u16)0;
      }
      *(ushort4*)&kkA[c][qd]      = make_ushort4(kp[0], kp[1], kp[2], kp[3]);
      *(ushort4*)&kkA[c + 48][qd] = make_ushort4(kn[0], kn[1], kn[2], kn[3]);
      *(ushort4*)&vB[c][qd]       = vq;       // v already bf16
    }
    __syncthreads();
#pragma unroll
    for (int ks = 0; ks < 2; ++ks) {
      bf16x8 af[3], bfr[2];
#pragma unroll
      for (int mi = 0; mi < 3; ++mi)
        af[mi] = *(const bf16x8*)&kkA[wr * 48 + mi * 16 + lm][ks * 32 + lq * 8];
#pragma unroll
      for (int ni = 0; ni < 2; ++ni)
        bfr[ni] = *(const bf16x8*)&vB[wc * 32 + ni * 16 + lm][ks * 32 + lq * 8];
#pragma unroll
      for (int mi = 0; mi < 3; ++mi)
#pragma unroll
        for (int ni = 0; ni < 2; ++ni)
          acc[mi][ni] = __builtin_amdgcn_mfma_f32_16x16x32_bf16(af[mi], bfr[ni], acc[mi][ni], 0, 0, 0);
    }
    __syncthreads();
  }
  const float inv_n = 1.0f / (float)NTOK;
#pragma unroll
  for (int mi = 0; mi < 3; ++mi)
#pragma unroll
    for (int ni = 0; ni < 2; ++ni) {
      const int n = wc * 32 + ni * 16 + lm;   // col = lane&15
#pragma unroll
      for (int reg = 0; reg < 4; ++reg) {
        const int m = wr * 48 + mi * 16 + lq * 4 + reg;  // row = quad*4+reg
        const float val = acc[mi][ni][reg] * inv_n;
        if (n < 48)       atomicAdd(&kvm[(size_t)bh * 96 * 48 + m * 48 + n], val);
        else if (n == 48) atomicAdd(&km[bh * 96 + m], val);
      }
    }
}

// ---------------- k3: q features, z-norm, x_sim/x_opp; attn -> ksT -----------------
__global__ __launch_bounds__(256) void k3_attn(
    const u16* __restrict__ qsT, u16* __restrict__ attnT,
    const float* __restrict__ km_g, const float* __restrict__ kvm_g,
    const void* __restrict__ power_p, const int* __restrict__ flag)
{
  const bool f32 = (*flag != 0);
  __shared__ __align__(16) float kvmL[96][48];
  __shared__ float kmL[96];
  __shared__ float pw[48];
  const int bh = blockIdx.y;
  const int b = bh >> 3, h = bh & 7;
  const int t = threadIdx.x;
  for (int i = t; i < 96 * 48; i += 256) kvmL[i / 48][i % 48] = kvm_g[(size_t)bh * 96 * 48 + i];
  if (t < 96) kmL[t] = km_g[bh * 96 + t];
  if (t < 48) pw[t] = 1.0f + 4.0f / (1.0f + expf(-ldx1(power_p, h * HDIM + t, f32)));
  __syncthreads();
  const int n = blockIdx.x * 512 + t;
  const size_t chan0 = ((size_t)(b * CDIM + h * HDIM)) * NTOK + n;
  const u16* qbase = qsT + chan0;
  u16* obase = attnT + chan0;
  float4 accs[2][6] = {}, acco[2][6] = {};
  float zs[2] = {}, zo[2] = {};
  for (int d = 0; d < 48; ++d) {
    const float p = pw[d];
    float qp[2], qn[2];
#pragma unroll
    for (int i = 0; i < 2; ++i) {
      const float qv = bf2f(qbase[(size_t)d * NTOK + i * 256]);
      const float f = pow_mag(fabsf(qv), p);
      qp[i] = (qv > 0.f) ? f : 0.f;
      qn[i] = (qv < 0.f) ? f : 0.f;
      zs[i] = fmaf(qp[i], kmL[d], zs[i]); zs[i] = fmaf(qn[i], kmL[d + 48], zs[i]);
      zo[i] = fmaf(qn[i], kmL[d], zo[i]); zo[i] = fmaf(qp[i], kmL[d + 48], zo[i]);
    }
#pragma unroll
    for (int e4 = 0; e4 < 6; ++e4) {
      const float4 kvA = *(const float4*)&kvmL[d][e4 * 4];
      const float4 kvB = *(const float4*)&kvmL[d + 48][e4 * 4];
      const float4 kvC = *(const float4*)&kvmL[d][24 + e4 * 4];
      const float4 kvD = *(const float4*)&kvmL[d + 48][24 + e4 * 4];
#pragma unroll
      for (int i = 0; i < 2; ++i) {
        accs[i][e4].x = fmaf(qp[i], kvA.x, fmaf(qn[i], kvB.x, accs[i][e4].x));
        accs[i][e4].y = fmaf(qp[i], kvA.y, fmaf(qn[i], kvB.y, accs[i][e4].y));
        accs[i][e4].z = fmaf(qp[i], kvA.z, fmaf(qn[i], kvB.z, accs[i][e4].z));
        accs[i][e4].w = fmaf(qp[i], kvA.w, fmaf(qn[i], kvB.w, accs[i][e4].w));
        acco[i][e4].x = fmaf(qn[i], kvC.x, fmaf(qp[i], kvD.x, acco[i][e4].x));
        acco[i][e4].y = fmaf(qn[i], kvC.y, fmaf(qp[i], kvD.y, acco[i][e4].y));
        acco[i][e4].z = fmaf(qn[i], kvC.z, fmaf(qp[i], kvD.z, acco[i][e4].z));
        acco[i][e4].w = fmaf(qn[i], kvC.w, fmaf(qp[i], kvD.w, acco[i][e4].w));
      }
    }
  }
#pragma unroll
  for (int i = 0; i < 2; ++i) {
    const float zsi = 1.0f / (zs[i] + 1e-6f);
    const float zoi = 1.0f / (zo[i] + 1e-6f);
#pragma unroll
    for (int e4 = 0; e4 < 6; ++e4) {
      const float4 s = accs[i][e4], o = acco[i][e4];
      obase[(size_t)(e4 * 4 + 0) * NTOK + i * 256]      = f2bf(s.x * zsi);
      obase[(size_t)(e4 * 4 + 1) * NTOK + i * 256]      = f2bf(s.y * zsi);
      obase[(size_t)(e4 * 4 + 2) * NTOK + i * 256]      = f2bf(s.z * zsi);
      obase[(size_t)(e4 * 4 + 3) * NTOK + i * 256]      = f2bf(s.w * zsi);
      obase[(size_t)(24 + e4 * 4 + 0) * NTOK + i * 256] = f2bf(o.x * zoi);
      obase[(size_t)(24 + e4 * 4 + 1) * NTOK + i * 256] = f2bf(o.y * zoi);
      obase[(size_t)(24 + e4 * 4 + 2) * NTOK + i * 256] = f2bf(o.z * zoi);
      obase[(size_t)(24 + e4 * 4 + 3) * NTOK + i * 256] = f2bf(o.w * zoi);
    }
  }
}

// ---------------- k4: 5x5 depthwise conv on vT + out2 = (attn + conv) * g ----------
__global__ __launch_bounds__(256) void k4_conv_combine(
    const u16* __restrict__ vT, const u16* __restrict__ gT,
    const void* __restrict__ dwc_w, const void* __restrict__ dwc_b,
    const int* __restrict__ flag,
    u16* __restrict__ attnT)
{
  const bool f32 = (*flag != 0);
  __shared__ float tile[20][128];
  const int bc = blockIdx.y;
  const int y0 = blockIdx.x * 16;
  const int t = threadIdx.x;
  const int d = bc % 48;
  float w[25];
#pragma unroll
  for (int i = 0; i < 25; ++i) w[i] = ldx1(dwc_w, d * 25 + i, f32);
  const float bias = ldx1(dwc_b, d, f32);
  const u16* vimg = vT + (size_t)bc * NTOK;
  for (int i = t; i < 20 * 128; i += 256) {
    const int r = i >> 7, xx = i & 127;
    const int gy = y0 + r - 2;
    tile[r][xx] = (gy >= 0 && gy < IMGH) ? bf2f(vimg[gy * IMGW + xx]) : 0.f;
  }
  __syncthreads();
  u16* abase = attnT + (size_t)bc * NTOK;
  const u16* gbase = gT + (size_t)bc * NTOK;
#pragma unroll
  for (int k = 0; k < 8; ++k) {
    const int px = t + k * 256;
    const int yy = px >> 7, xcol = px & 127;
    float acc = bias;
#pragma unroll
    for (int dy = 0; dy < 5; ++dy)
#pragma unroll
      for (int dx = 0; dx < 5; ++dx) {
        const int ux = xcol + dx - 2;
        const float val = (ux >= 0 && ux < IMGW) ? tile[yy + dy][ux] : 0.f;
        acc = fmaf(w[dy * 5 + dx], val, acc);
      }
    const int gidx = (y0 + yy) * IMGW + xcol;
    abase[gidx] = f2bf((bf2f(abase[gidx]) + acc) * bf2f(gbase[gidx]));
  }
}

// ---------------- k4b: transpose out2 channel-major -> token-major -----------------
__global__ __launch_bounds__(256) void k4b_transpose(
    const u16* __restrict__ src, u16* __restrict__ dst)
{
  __shared__ u16 tile[64][68];
  const int b  = blockIdx.z;
  const int c0 = blockIdx.y * 64;
  const int n0 = blockIdx.x * 64;
  const int t = threadIdx.x;
  const int tr = t >> 4, tq = t & 15;
#pragma unroll
  for (int i = 0; i < 4; ++i) {
    const int r = tr + i * 16;
    *(ushort4*)&tile[r][tq * 4] =
        *(const ushort4*)(src + ((size_t)(b * CDIM + c0 + r)) * NTOK + n0 + tq * 4);
  }
  __syncthreads();
#pragma unroll
  for (int i = 0; i < 4; ++i) {
    const int n = tr + i * 16;
    const ushort4 vv = make_ushort4(tile[tq * 4 + 0][n], tile[tq * 4 + 1][n],
                                    tile[tq * 4 + 2][n], tile[tq * 4 + 3][n]);
    *(ushort4*)(dst + ((size_t)(b * NTOK + n0 + n)) * CDIM + c0 + tq * 4) = vv;
  }
}

// ---------------- k5: MFMA GEMM out2_tm @ Wproj + b -> d_out, reg-prefetch ---------
__global__ __launch_bounds__(256) void k5_mfma(
    const u16* __restrict__ A, const u16* __restrict__ WpT,
    const void* __restrict__ bp, const int* __restrict__ flag,
    void* __restrict__ out)
{
  const bool f32 = (*flag != 0);
  __shared__ __align__(16) u16 Asm[128 * 64];
  __shared__ __align__(16) u16 Bsm[128 * 64];
  const int t = threadIdx.x;
  const int n0 = blockIdx.x * 128;
  const int m0 = blockIdx.y * 128;
  const int wave = t >> 6, lane = t & 63;
  const int wr = wave >> 1, wc = wave & 1;
  const int lm = lane & 15, lq = lane >> 4;

  int ro[4], co[4], lo[4];
#pragma unroll
  for (int i = 0; i < 4; ++i) {
    const int chunk = t + i * 256;
    ro[i] = chunk >> 3; co[i] = chunk & 7;
    lo[i] = ro[i] * 64 + ((co[i] ^ (ro[i] & 7)) * 8);
  }

  f32x4 acc[4][4] = {};
  uint4 aU[4], bU[4];
#pragma unroll
  for (int i = 0; i < 4; ++i) {
    aU[i] = *(const uint4*)(A + (size_t)(m0 + ro[i]) * CDIM + co[i] * 8);
    bU[i] = *(const uint4*)(WpT + (size_t)(n0 + ro[i]) * CDIM + co[i] * 8);
  }

  for (int k0 = 0; k0 < CDIM; k0 += 64) {
    if (k0) __syncthreads();
#pragma unroll
    for (int i = 0; i < 4; ++i) {
      *(uint4*)&Asm[lo[i]] = aU[i];
      *(uint4*)&Bsm[lo[i]] = bU[i];
    }
    __syncthreads();
    if (k0 < CDIM - 64) {
      const int kn = k0 + 64;
#pragma unroll
      for (int i = 0; i < 4; ++i) {
        aU[i] = *(const uint4*)(A + (size_t)(m0 + ro[i]) * CDIM + kn + co[i] * 8);
        bU[i] = *(const uint4*)(WpT + (size_t)(n0 + ro[i]) * CDIM + kn + co[i] * 8);
      }
    }
#pragma unroll
    for (int kh = 0; kh < 2; ++kh) {
      bf16x8 af[4], bfr[4];
#pragma unroll
      for (int r = 0; r < 4; ++r) {
        const int row = wr * 64 + r * 16 + lm;
        af[r] = *(const bf16x8*)&Asm[row * 64 + (((kh * 4 + lq) ^ (row & 7)) * 8)];
      }
#pragma unroll
      for (int cb = 0; cb < 4; ++cb) {
        const int row = wc * 64 + cb * 16 + lm;
        bfr[cb] = *(const bf16x8*)&Bsm[row * 64 + (((kh * 4 + lq) ^ (row & 7)) * 8)];
      }
#pragma unroll
      for (int r = 0; r < 4; ++r)
#pragma unroll
        for (int cb = 0; cb < 4; ++cb)
          acc[r][cb] = __builtin_amdgcn_mfma_f32_16x16x32_bf16(af[r], bfr[cb], acc[r][cb], 0, 0, 0);
    }
  }
#pragma unroll
  for (int cb = 0; cb < 4; ++cb) {
    const int cg = n0 + wc * 64 + cb * 16 + lm;
    const float bb = ldx1(bp, cg, f32);
#pragma unroll
    for (int r = 0; r < 4; ++r) {
      const int rowtok = m0 + wr * 64 + r * 16 + lq * 4;
      const f32x4 v = acc[r][cb];
#pragma unroll
      for (int reg = 0; reg < 4; ++reg) {
        const size_t o = (size_t)(rowtok + reg) * CDIM + cg;
        if (f32) ((float*)out)[o] = v[reg] + bb;
        else     ((u16*)out)[o]   = f2bf(v[reg] + bb);
      }
    }
  }
}

extern "C" void kernel_launch(void* const* d_in, const int* in_sizes, int n_in,
                              void* d_out, int out_size, void* d_ws, size_t ws_size,
                              hipStream_t stream) {
  const void* x       = d_in[0];
  const void* Wqg     = d_in[1];
  const void* Wkv     = d_in[2];
  const void* Wproj   = d_in[3];
  const void* bproj   = d_in[4];
  const void* pos_enc = d_in[5];
  const void* power_p = d_in[6];
  const void* scale_p = d_in[7];
  const void* dwc_w   = d_in[8];
  const void* dwc_b   = d_in[9];

  const size_t S = (size_t)NB * NTOK * CDIM;
  const size_t stats_off   = 256;
  const size_t stats_bytes = (size_t)(32 * 96 + 32 * 96 * 48) * sizeof(float);
  const size_t w2t_elems = 1536 * 384, wpt_elems = 384 * 384;
  const size_t need = stats_off + stats_bytes + 3 * S * sizeof(u16)
                    + (w2t_elems + wpt_elems) * sizeof(u16);
  if (ws_size < need) return;

  int*   flag = (int*)d_ws;
  float* km   = (float*)((char*)d_ws + stats_off);
  float* kvm  = km + 32 * 96;
  u16* qsT = (u16*)((char*)d_ws + stats_off + stats_bytes);
  u16* gT  = qsT + S;
  u16* ksT = gT + S;
  u16* W2T = ksT + S;
  u16* WpT = W2T + w2t_elems;
  u16* vT  = (u16*)d_out;

  hipMemsetAsync(km, 0, stats_bytes, stream);

  k0_detect<<<1, 256, 0, stream>>>(x, flag);
  kprep<<<(int)((w2t_elems + wpt_elems + 255) / 256), 256, 0, stream>>>(
      Wqg, Wkv, Wproj, flag, W2T, WpT);
  k1_mfma<<<dim3(12, 512), 256, 0, stream>>>(x, W2T, pos_enc, scale_p, flag,
                                             qsT, gT, ksT, vT);
  k2_stats<<<dim3(32, 16), 256, 0, stream>>>(ksT, vT, power_p, flag, km, kvm);
  k3_attn<<<dim3(32, 32), 256, 0, stream>>>(qsT, ksT, km, kvm, power_p, flag);
  k4_conv_combine<<<dim3(8, 1536), 256, 0, stream>>>(vT, gT, dwc_w, dwc_b, flag, ksT);
  k4b_transpose<<<dim3(256, 6, 4), 256, 0, stream>>>(ksT, qsT);
  k5_mfma<<<dim3(3, 512), 256, 0, stream>>>(qsT, WpT, bproj, flag, d_out);
}